// Round 1
// baseline (265.520 us; speedup 1.0000x reference)
//
#include <hip/hip_runtime.h>

typedef __bf16 bf16_t;
typedef __bf16 bf16x8 __attribute__((ext_vector_type(8)));
typedef __bf16 bf16x4 __attribute__((ext_vector_type(4)));
typedef float f32x4 __attribute__((ext_vector_type(4)));

#define NE 8192
#define NN 2048
#define HH 256

__device__ inline f32x4 mfma_bf16(bf16x8 a, bf16x8 b, f32x4 c) {
    return __builtin_amdgcn_mfma_f32_16x16x32_bf16(a, b, c, 0, 0, 0);
}

// ---------------------------------------------------------------------------
// convert fp32 -> bf16 for edge_features + 5 weight matrices
// grid 2048 x 256 : each thread handles one float4 slot (524288 total = ebf)
// ---------------------------------------------------------------------------
__device__ inline bf16x4 cvt4(float4 v) {
    bf16x4 o;
    o[0] = (bf16_t)v.x; o[1] = (bf16_t)v.y; o[2] = (bf16_t)v.z; o[3] = (bf16_t)v.w;
    return o;
}

__global__ __launch_bounds__(256)
void convert_kernel(const float* __restrict__ ef, const float* __restrict__ wq,
                    const float* __restrict__ wo, const float* __restrict__ w1,
                    const float* __restrict__ w2, const float* __restrict__ wn,
                    bf16_t* __restrict__ ebf, bf16_t* __restrict__ bwq,
                    bf16_t* __restrict__ bwo, bf16_t* __restrict__ bw1,
                    bf16_t* __restrict__ bw2, bf16_t* __restrict__ bwn) {
    int i = blockIdx.x * 256 + threadIdx.x;   // 0 .. 524287
    ((bf16x4*)ebf)[i] = cvt4(((const float4*)ef)[i]);
    if (i < 49152) ((bf16x4*)bwq)[i] = cvt4(((const float4*)wq)[i]);
    if (i < 16384) {
        ((bf16x4*)bwo)[i] = cvt4(((const float4*)wo)[i]);
        ((bf16x4*)bw1)[i] = cvt4(((const float4*)w1)[i]);
        ((bf16x4*)bw2)[i] = cvt4(((const float4*)w2)[i]);
        ((bf16x4*)bwn)[i] = cvt4(((const float4*)wn)[i]);
    }
}

// ---------------------------------------------------------------------------
// Generic bf16 GEMM: C = act(A * B^T + bias)  [A: MxK, B: NxK row-major]
// 64x64 tile, BK=64, 256 threads (4 waves, each a 32x32 quadrant)
// OUTKIND: 0 = fp32 out, 1 = bf16 out, 2 = fp32 out with node epilogue
//          (out = resid + relu(val))
// ---------------------------------------------------------------------------
template<int ACT, int OUTKIND>
__global__ __launch_bounds__(256)
void gemm_kernel(const bf16_t* __restrict__ A, const bf16_t* __restrict__ B,
                 const float* __restrict__ bias, void* __restrict__ out,
                 const float* __restrict__ resid, int M, int N, int K) {
    __shared__ bf16_t As[64][72];
    __shared__ bf16_t Bs[64][72];
    int tid = threadIdx.x;
    int w = tid >> 6, l = tid & 63, hi = l >> 4, c15 = l & 15;
    int wr = w >> 1, wc = w & 1;
    int brow = blockIdx.x * 64, bcol = blockIdx.y * 64;
    int r = tid >> 2, s = tid & 3;

    f32x4 acc[2][2] = {};

    for (int k0 = 0; k0 < K; k0 += 64) {
        __syncthreads();
        bf16x8 a0 = *(const bf16x8*)&A[(long)(brow + r) * K + k0 + s * 16];
        bf16x8 a1 = *(const bf16x8*)&A[(long)(brow + r) * K + k0 + s * 16 + 8];
        bf16x8 b0 = *(const bf16x8*)&B[(long)(bcol + r) * K + k0 + s * 16];
        bf16x8 b1 = *(const bf16x8*)&B[(long)(bcol + r) * K + k0 + s * 16 + 8];
        *(bf16x8*)&As[r][s * 16]     = a0;
        *(bf16x8*)&As[r][s * 16 + 8] = a1;
        *(bf16x8*)&Bs[r][s * 16]     = b0;
        *(bf16x8*)&Bs[r][s * 16 + 8] = b1;
        __syncthreads();
#pragma unroll
        for (int c = 0; c < 2; ++c) {
            bf16x8 af0 = *(const bf16x8*)&As[wr * 32 + c15][c * 32 + hi * 8];
            bf16x8 af1 = *(const bf16x8*)&As[wr * 32 + 16 + c15][c * 32 + hi * 8];
            bf16x8 bf0 = *(const bf16x8*)&Bs[wc * 32 + c15][c * 32 + hi * 8];
            bf16x8 bf1 = *(const bf16x8*)&Bs[wc * 32 + 16 + c15][c * 32 + hi * 8];
            acc[0][0] = mfma_bf16(af0, bf0, acc[0][0]);
            acc[0][1] = mfma_bf16(af0, bf1, acc[0][1]);
            acc[1][0] = mfma_bf16(af1, bf0, acc[1][0]);
            acc[1][1] = mfma_bf16(af1, bf1, acc[1][1]);
        }
    }

#pragma unroll
    for (int i = 0; i < 2; ++i)
#pragma unroll
        for (int j = 0; j < 2; ++j)
#pragma unroll
            for (int rg = 0; rg < 4; ++rg) {
                int row = brow + wr * 32 + i * 16 + hi * 4 + rg;
                int col = bcol + wc * 32 + j * 16 + c15;
                float v = acc[i][j][rg] + bias[col];
                if (ACT) v = fmaxf(v, 0.0f);
                if (OUTKIND == 0) {
                    ((float*)out)[(long)row * N + col] = v;
                } else if (OUTKIND == 1) {
                    ((bf16_t*)out)[(long)row * N + col] = (bf16_t)v;
                } else {
                    ((float*)out)[(long)row * N + col] =
                        resid[(long)row * N + col] + fmaxf(v, 0.0f);
                }
            }
}

// ---------------------------------------------------------------------------
// Flash attention (no-max online softmax: scores are tiny, |s|<~3)
// grid = 256 blocks (head = b&3, qtile = b>>2, 128 q-rows/block)
// 512 threads = 8 waves x 16 q-rows
// ---------------------------------------------------------------------------
__global__ __launch_bounds__(512)
void attn_kernel(const bf16_t* __restrict__ qkv, bf16_t* __restrict__ ctx) {
    __shared__ bf16_t Ks[64][72];
    __shared__ bf16_t Vt[64][72];
    __shared__ bf16_t Ps[8][16][72];

    int b = blockIdx.x;
    int h = b & 3, qt = b >> 2;
    int q0 = qt * 128;
    int tid = threadIdx.x, w = tid >> 6, l = tid & 63, hi = l >> 4, c15 = l & 15;

    int qrow = q0 + w * 16 + c15;
    bf16x8 qf0 = *(const bf16x8*)&qkv[(long)qrow * 768 + h * 64 + hi * 8];
    bf16x8 qf1 = *(const bf16x8*)&qkv[(long)qrow * 768 + h * 64 + 32 + hi * 8];

    f32x4 O[4] = {};
    float ls[4] = {0.f, 0.f, 0.f, 0.f};

    int kr = tid >> 2, kss = tid & 3;        // K staging (threads 0..255)
    int u = tid - 256, vkv = u & 63, vdh = u >> 6;  // V staging (256..511)

    for (int kt = 0; kt < NE; kt += 64) {
        __syncthreads();
        if (tid < 256) {
            const bf16_t* src = &qkv[(long)(kt + kr) * 768 + 256 + h * 64 + kss * 16];
            bf16x8 k0 = *(const bf16x8*)src;
            bf16x8 k1 = *(const bf16x8*)(src + 8);
            *(bf16x8*)&Ks[kr][kss * 16]     = k0;
            *(bf16x8*)&Ks[kr][kss * 16 + 8] = k1;
        } else {
            const bf16_t* src = &qkv[(long)(kt + vkv) * 768 + 512 + h * 64 + vdh * 16];
            bf16x8 v0 = *(const bf16x8*)src;
            bf16x8 v1 = *(const bf16x8*)(src + 8);
#pragma unroll
            for (int j = 0; j < 8; ++j) Vt[vdh * 16 + j][vkv] = v0[j];
#pragma unroll
            for (int j = 0; j < 8; ++j) Vt[vdh * 16 + 8 + j][vkv] = v1[j];
        }
        __syncthreads();

        // S = Q K^T   (rows: this wave's 16 q-rows, cols: 64 kv)
        f32x4 S[4];
#pragma unroll
        for (int g = 0; g < 4; ++g) {
            bf16x8 kf0 = *(const bf16x8*)&Ks[g * 16 + c15][hi * 8];
            bf16x8 kf1 = *(const bf16x8*)&Ks[g * 16 + c15][32 + hi * 8];
            f32x4 z = {};
            z = mfma_bf16(qf0, kf0, z);
            z = mfma_bf16(qf1, kf1, z);
            S[g] = z;
        }

        // P = exp(S/8), accumulate row-sum partials, spill P to per-wave LDS
#pragma unroll
        for (int g = 0; g < 4; ++g)
#pragma unroll
            for (int rg = 0; rg < 4; ++rg) {
                float p = __expf(S[g][rg] * 0.125f);
                ls[rg] += p;
                Ps[w][hi * 4 + rg][g * 16 + c15] = (bf16_t)p;
            }
        asm volatile("s_waitcnt lgkmcnt(0)" ::: "memory");
        __builtin_amdgcn_sched_barrier(0);

        // O += P V
        bf16x8 pf0 = *(const bf16x8*)&Ps[w][c15][hi * 8];
        bf16x8 pf1 = *(const bf16x8*)&Ps[w][c15][32 + hi * 8];
#pragma unroll
        for (int g = 0; g < 4; ++g) {
            bf16x8 vf0 = *(const bf16x8*)&Vt[g * 16 + c15][hi * 8];
            bf16x8 vf1 = *(const bf16x8*)&Vt[g * 16 + c15][32 + hi * 8];
            O[g] = mfma_bf16(pf0, vf0, O[g]);
            O[g] = mfma_bf16(pf1, vf1, O[g]);
        }
    }

    // finish row sums (reduce over the 16 lanes sharing hi)
#pragma unroll
    for (int rg = 0; rg < 4; ++rg) {
        float s = ls[rg];
        s += __shfl_xor(s, 1);
        s += __shfl_xor(s, 2);
        s += __shfl_xor(s, 4);
        s += __shfl_xor(s, 8);
        ls[rg] = s;
    }

#pragma unroll
    for (int g = 0; g < 4; ++g)
#pragma unroll
        for (int rg = 0; rg < 4; ++rg) {
            int row = q0 + w * 16 + hi * 4 + rg;
            int col = h * 64 + g * 16 + c15;
            ctx[(long)row * 256 + col] = (bf16_t)(O[g][rg] / ls[rg]);
        }
}

// ---------------------------------------------------------------------------
// LayerNorm over rows of 256: out = LN(x + y) * g + b; optional bf16 copy
// grid 2048 x 256 : 4 rows/block, one wave per row, 4 cols/lane
// ---------------------------------------------------------------------------
__global__ __launch_bounds__(256)
void ln_kernel(const float* __restrict__ x, const float* __restrict__ y,
               const float* __restrict__ g, const float* __restrict__ b,
               float* __restrict__ outf, bf16_t* __restrict__ outb) {
    int row = blockIdx.x * 4 + (threadIdx.x >> 6);
    int l = threadIdx.x & 63;
    float4 v = ((const float4*)&x[(long)row * 256])[l];
    float4 uu = ((const float4*)&y[(long)row * 256])[l];
    float a0 = v.x + uu.x, a1 = v.y + uu.y, a2 = v.z + uu.z, a3 = v.w + uu.w;

    float s = a0 + a1 + a2 + a3;
#pragma unroll
    for (int off = 1; off < 64; off <<= 1) s += __shfl_xor(s, off);
    float mu = s * (1.0f / 256.0f);

    float d0 = a0 - mu, d1 = a1 - mu, d2 = a2 - mu, d3 = a3 - mu;
    float q = d0 * d0 + d1 * d1 + d2 * d2 + d3 * d3;
#pragma unroll
    for (int off = 1; off < 64; off <<= 1) q += __shfl_xor(q, off);
    float rs = rsqrtf(q * (1.0f / 256.0f) + 1e-5f);

    float4 gg = ((const float4*)g)[l];
    float4 bb = ((const float4*)b)[l];
    float o0 = d0 * rs * gg.x + bb.x;
    float o1 = d1 * rs * gg.y + bb.y;
    float o2 = d2 * rs * gg.z + bb.z;
    float o3 = d3 * rs * gg.w + bb.w;
    float4 ov; ov.x = o0; ov.y = o1; ov.z = o2; ov.w = o3;
    ((float4*)&outf[(long)row * 256])[l] = ov;
    if (outb) {
        bf16x4 ob;
        ob[0] = (bf16_t)o0; ob[1] = (bf16_t)o1; ob[2] = (bf16_t)o2; ob[3] = (bf16_t)o3;
        ((bf16x4*)&outb[(long)row * 256])[l] = ob;
    }
}

// ---------------------------------------------------------------------------
// scatter-add e rows into per-node accumulators (+counts)
// ---------------------------------------------------------------------------
__global__ __launch_bounds__(256)
void scatter_kernel(const float* __restrict__ e, const int* __restrict__ ei,
                    float* __restrict__ acc, float* __restrict__ cnt) {
    int edge = blockIdx.x;
    int dst = ei[NE + edge];
    int t = threadIdx.x;
    atomicAdd(&acc[(long)dst * 256 + t], e[(long)edge * 256 + t]);
    if (t == 0) atomicAdd(&cnt[dst], 1.0f);
}

// updates = acc / max(cnt,1) -> bf16
__global__ __launch_bounds__(256)
void upd_kernel(const float* __restrict__ acc, const float* __restrict__ cnt,
                bf16_t* __restrict__ ub) {
    int i = blockIdx.x * 256 + threadIdx.x;   // 2048 blocks -> 524288 = NN*HH
    int row = i >> 8;
    ub[i] = (bf16_t)(acc[i] / fmaxf(cnt[row], 1.0f));
}

// ---------------------------------------------------------------------------
extern "C" void kernel_launch(void* const* d_in, const int* in_sizes, int n_in,
                              void* d_out, int out_size, void* d_ws, size_t ws_size,
                              hipStream_t stream) {
    const float* node_features = (const float*)d_in[0];
    const float* edge_features = (const float*)d_in[1];
    const float* in_proj_w  = (const float*)d_in[2];
    const float* in_proj_b  = (const float*)d_in[3];
    const float* out_proj_w = (const float*)d_in[4];
    const float* out_proj_b = (const float*)d_in[5];
    const float* mlp_w1 = (const float*)d_in[6];
    const float* mlp_b1 = (const float*)d_in[7];
    const float* mlp_w2 = (const float*)d_in[8];
    const float* mlp_b2 = (const float*)d_in[9];
    const float* nu_w   = (const float*)d_in[10];
    const float* nu_b   = (const float*)d_in[11];
    const float* ln1_g  = (const float*)d_in[12];
    const float* ln1_b  = (const float*)d_in[13];
    const float* ln2_g  = (const float*)d_in[14];
    const float* ln2_b  = (const float*)d_in[15];
    const int*   edge_index = (const int*)d_in[16];

    char* ws = (char*)d_ws;
    size_t off = 0;
    auto alloc = [&](size_t bytes) {
        char* p = ws + off;
        off = (off + bytes + 255) & ~(size_t)255;
        return p;
    };
    bf16_t* ebf   = (bf16_t*)alloc(NE * HH * 2);           // edge_features bf16
    bf16_t* bwq   = (bf16_t*)alloc(768 * 256 * 2);
    bf16_t* bwo   = (bf16_t*)alloc(256 * 256 * 2);
    bf16_t* bw1   = (bf16_t*)alloc(256 * 256 * 2);
    bf16_t* bw2   = (bf16_t*)alloc(256 * 256 * 2);
    bf16_t* bwn   = (bf16_t*)alloc(256 * 256 * 2);
    bf16_t* qkv   = (bf16_t*)alloc((size_t)NE * 768 * 2);
    bf16_t* ctx   = (bf16_t*)alloc((size_t)NE * HH * 2);
    float*  attended = (float*)alloc((size_t)NE * HH * 4);
    float*  e1f   = (float*)alloc((size_t)NE * HH * 4);
    bf16_t* e1b   = (bf16_t*)alloc((size_t)NE * HH * 2);
    bf16_t* hbuf  = (bf16_t*)alloc((size_t)NE * HH * 2);
    float*  mlpout = (float*)alloc((size_t)NE * HH * 4);
    float*  acc   = (float*)alloc((size_t)(NN * HH + NN) * 4);  // acc + cnt contiguous
    float*  cnt   = acc + (size_t)NN * HH;
    bf16_t* updb  = (bf16_t*)alloc((size_t)NN * HH * 2);

    float* nout = (float*)d_out;
    float* eout = (float*)d_out + (size_t)NN * HH;

    convert_kernel<<<2048, 256, 0, stream>>>(edge_features, in_proj_w, out_proj_w,
                                             mlp_w1, mlp_w2, nu_w,
                                             ebf, bwq, bwo, bw1, bw2, bwn);

    // qkv = ebf @ in_proj_w^T + b  -> bf16 [NE,768]
    gemm_kernel<0, 1><<<dim3(NE / 64, 768 / 64), 256, 0, stream>>>(
        ebf, bwq, in_proj_b, qkv, nullptr, NE, 768, 256);

    attn_kernel<<<256, 512, 0, stream>>>(qkv, ctx);

    // attended = ctx @ out_proj_w^T + b -> fp32
    gemm_kernel<0, 0><<<dim3(NE / 64, 256 / 64), 256, 0, stream>>>(
        ctx, bwo, out_proj_b, attended, nullptr, NE, 256, 256);

    // e1 = LN(edge_features + attended)
    ln_kernel<<<NE / 4, 256, 0, stream>>>(edge_features, attended, ln1_g, ln1_b,
                                          e1f, e1b);

    // h = relu(e1 @ w1^T + b1) -> bf16
    gemm_kernel<1, 1><<<dim3(NE / 64, 256 / 64), 256, 0, stream>>>(
        e1b, bw1, mlp_b1, hbuf, nullptr, NE, 256, 256);

    // mlpout = h @ w2^T + b2 -> fp32
    gemm_kernel<0, 0><<<dim3(NE / 64, 256 / 64), 256, 0, stream>>>(
        hbuf, bw2, mlp_b2, mlpout, nullptr, NE, 256, 256);

    // e = LN(e1 + mlpout) -> d_out (second output)
    ln_kernel<<<NE / 4, 256, 0, stream>>>(e1f, mlpout, ln2_g, ln2_b,
                                          eout, (bf16_t*)nullptr);

    // scatter mean
    hipMemsetAsync(acc, 0, (size_t)(NN * HH + NN) * 4, stream);
    scatter_kernel<<<NE, 256, 0, stream>>>(eout, edge_index, acc, cnt);
    upd_kernel<<<NN * HH / 256, 256, 0, stream>>>(acc, cnt, updb);

    // n = node_features + relu(updates @ nu_w^T + nu_b) -> d_out (first output)
    gemm_kernel<0, 2><<<dim3(NN / 64, 256 / 64), 256, 0, stream>>>(
        updb, bwn, nu_b, nout, node_features, NN, 256, 256);
}

// Round 2
// 210.458 us; speedup vs baseline: 1.2616x; 1.2616x over previous
//
#include <hip/hip_runtime.h>

typedef __bf16 bf16_t;
typedef __bf16 bf16x8 __attribute__((ext_vector_type(8)));
typedef __bf16 bf16x4 __attribute__((ext_vector_type(4)));
typedef float f32x4 __attribute__((ext_vector_type(4)));

#define NE 8192
#define NN 2048
#define HH 256
#define NSPLIT 4

__device__ inline f32x4 mfma_bf16(bf16x8 a, bf16x8 b, f32x4 c) {
    return __builtin_amdgcn_mfma_f32_16x16x32_bf16(a, b, c, 0, 0, 0);
}

// ---------------------------------------------------------------------------
// convert fp32 -> bf16 for edge_features + 5 weight matrices
// ---------------------------------------------------------------------------
__device__ inline bf16x4 cvt4(float4 v) {
    bf16x4 o;
    o[0] = (bf16_t)v.x; o[1] = (bf16_t)v.y; o[2] = (bf16_t)v.z; o[3] = (bf16_t)v.w;
    return o;
}

__global__ __launch_bounds__(256)
void convert_kernel(const float* __restrict__ ef, const float* __restrict__ wq,
                    const float* __restrict__ wo, const float* __restrict__ w1,
                    const float* __restrict__ w2, const float* __restrict__ wn,
                    bf16_t* __restrict__ ebf, bf16_t* __restrict__ bwq,
                    bf16_t* __restrict__ bwo, bf16_t* __restrict__ bw1,
                    bf16_t* __restrict__ bw2, bf16_t* __restrict__ bwn) {
    int i = blockIdx.x * 256 + threadIdx.x;   // 0 .. 524287
    ((bf16x4*)ebf)[i] = cvt4(((const float4*)ef)[i]);
    if (i < 49152) ((bf16x4*)bwq)[i] = cvt4(((const float4*)wq)[i]);
    if (i < 16384) {
        ((bf16x4*)bwo)[i] = cvt4(((const float4*)wo)[i]);
        ((bf16x4*)bw1)[i] = cvt4(((const float4*)w1)[i]);
        ((bf16x4*)bw2)[i] = cvt4(((const float4*)w2)[i]);
        ((bf16x4*)bwn)[i] = cvt4(((const float4*)wn)[i]);
    }
}

// ---------------------------------------------------------------------------
// Generic bf16 GEMM: C = act(A * B^T + bias)  [A: MxK, B: NxK row-major]
// 64x64 tile, BK=64, 256 threads (4 waves, each a 32x32 quadrant)
// ---------------------------------------------------------------------------
template<int ACT, int OUTKIND>
__global__ __launch_bounds__(256)
void gemm_kernel(const bf16_t* __restrict__ A, const bf16_t* __restrict__ B,
                 const float* __restrict__ bias, void* __restrict__ out,
                 const float* __restrict__ resid, int M, int N, int K) {
    __shared__ bf16_t As[64][72];
    __shared__ bf16_t Bs[64][72];
    int tid = threadIdx.x;
    int w = tid >> 6, l = tid & 63, hi = l >> 4, c15 = l & 15;
    int wr = w >> 1, wc = w & 1;
    int brow = blockIdx.x * 64, bcol = blockIdx.y * 64;
    int r = tid >> 2, s = tid & 3;

    f32x4 acc[2][2] = {};

    for (int k0 = 0; k0 < K; k0 += 64) {
        __syncthreads();
        bf16x8 a0 = *(const bf16x8*)&A[(long)(brow + r) * K + k0 + s * 16];
        bf16x8 a1 = *(const bf16x8*)&A[(long)(brow + r) * K + k0 + s * 16 + 8];
        bf16x8 b0 = *(const bf16x8*)&B[(long)(bcol + r) * K + k0 + s * 16];
        bf16x8 b1 = *(const bf16x8*)&B[(long)(bcol + r) * K + k0 + s * 16 + 8];
        *(bf16x8*)&As[r][s * 16]     = a0;
        *(bf16x8*)&As[r][s * 16 + 8] = a1;
        *(bf16x8*)&Bs[r][s * 16]     = b0;
        *(bf16x8*)&Bs[r][s * 16 + 8] = b1;
        __syncthreads();
#pragma unroll
        for (int c = 0; c < 2; ++c) {
            bf16x8 af0 = *(const bf16x8*)&As[wr * 32 + c15][c * 32 + hi * 8];
            bf16x8 af1 = *(const bf16x8*)&As[wr * 32 + 16 + c15][c * 32 + hi * 8];
            bf16x8 bf0 = *(const bf16x8*)&Bs[wc * 32 + c15][c * 32 + hi * 8];
            bf16x8 bf1 = *(const bf16x8*)&Bs[wc * 32 + 16 + c15][c * 32 + hi * 8];
            acc[0][0] = mfma_bf16(af0, bf0, acc[0][0]);
            acc[0][1] = mfma_bf16(af0, bf1, acc[0][1]);
            acc[1][0] = mfma_bf16(af1, bf0, acc[1][0]);
            acc[1][1] = mfma_bf16(af1, bf1, acc[1][1]);
        }
    }

#pragma unroll
    for (int i = 0; i < 2; ++i)
#pragma unroll
        for (int j = 0; j < 2; ++j)
#pragma unroll
            for (int rg = 0; rg < 4; ++rg) {
                int row = brow + wr * 32 + i * 16 + hi * 4 + rg;
                int col = bcol + wc * 32 + j * 16 + c15;
                float v = acc[i][j][rg] + bias[col];
                if (ACT) v = fmaxf(v, 0.0f);
                if (OUTKIND == 0) {
                    ((float*)out)[(long)row * N + col] = v;
                } else if (OUTKIND == 1) {
                    ((bf16_t*)out)[(long)row * N + col] = (bf16_t)v;
                } else {
                    ((float*)out)[(long)row * N + col] =
                        resid[(long)row * N + col] + fmaxf(v, 0.0f);
                }
            }
}

// ---------------------------------------------------------------------------
// Flash attention, KV-split for occupancy.
// grid = dim3(256, NSPLIT): blockIdx.x -> (head = &3, qtile = >>2, 128 q-rows)
//        blockIdx.y -> kv split (NE/NSPLIT rows each)
// 512 threads = 8 waves x 16 q-rows.
// No-max softmax (scores tiny): partial unnormalized O and row-sum l are pure
// sums over kv -> combine across splits with fp32 atomics, normalize after.
// ---------------------------------------------------------------------------
__global__ __launch_bounds__(512)
void attn_kernel(const bf16_t* __restrict__ qkv, float* __restrict__ Oacc,
                 float* __restrict__ lacc) {
    __shared__ bf16_t Ks[64][72];
    __shared__ bf16_t Vt[64][72];
    __shared__ bf16_t Ps[8][16][72];

    int b = blockIdx.x;
    int h = b & 3, qt = b >> 2;
    int q0 = qt * 128;
    int tid = threadIdx.x, w = tid >> 6, l = tid & 63, hi = l >> 4, c15 = l & 15;

    int qrow = q0 + w * 16 + c15;
    bf16x8 qf0 = *(const bf16x8*)&qkv[(long)qrow * 768 + h * 64 + hi * 8];
    bf16x8 qf1 = *(const bf16x8*)&qkv[(long)qrow * 768 + h * 64 + 32 + hi * 8];

    f32x4 O[4] = {};
    float ls[4] = {0.f, 0.f, 0.f, 0.f};

    int kr = tid >> 2, kss = tid & 3;               // K staging (threads 0..255)
    int u = tid - 256, vkv = u & 63, vdh = u >> 6;  // V staging (256..511)

    int kbeg = blockIdx.y * (NE / NSPLIT);
    int kend = kbeg + NE / NSPLIT;

    for (int kt = kbeg; kt < kend; kt += 64) {
        __syncthreads();
        if (tid < 256) {
            const bf16_t* src = &qkv[(long)(kt + kr) * 768 + 256 + h * 64 + kss * 16];
            bf16x8 k0 = *(const bf16x8*)src;
            bf16x8 k1 = *(const bf16x8*)(src + 8);
            *(bf16x8*)&Ks[kr][kss * 16]     = k0;
            *(bf16x8*)&Ks[kr][kss * 16 + 8] = k1;
        } else {
            const bf16_t* src = &qkv[(long)(kt + vkv) * 768 + 512 + h * 64 + vdh * 16];
            bf16x8 v0 = *(const bf16x8*)src;
            bf16x8 v1 = *(const bf16x8*)(src + 8);
#pragma unroll
            for (int j = 0; j < 8; ++j) Vt[vdh * 16 + j][vkv] = v0[j];
#pragma unroll
            for (int j = 0; j < 8; ++j) Vt[vdh * 16 + 8 + j][vkv] = v1[j];
        }
        __syncthreads();

        // S = Q K^T   (rows: this wave's 16 q-rows, cols: 64 kv)
        f32x4 S[4];
#pragma unroll
        for (int g = 0; g < 4; ++g) {
            bf16x8 kf0 = *(const bf16x8*)&Ks[g * 16 + c15][hi * 8];
            bf16x8 kf1 = *(const bf16x8*)&Ks[g * 16 + c15][32 + hi * 8];
            f32x4 z = {};
            z = mfma_bf16(qf0, kf0, z);
            z = mfma_bf16(qf1, kf1, z);
            S[g] = z;
        }

        // P = exp(S/8), accumulate row-sum partials, spill P to per-wave LDS
#pragma unroll
        for (int g = 0; g < 4; ++g)
#pragma unroll
            for (int rg = 0; rg < 4; ++rg) {
                float p = __expf(S[g][rg] * 0.125f);
                ls[rg] += p;
                Ps[w][hi * 4 + rg][g * 16 + c15] = (bf16_t)p;
            }
        asm volatile("s_waitcnt lgkmcnt(0)" ::: "memory");
        __builtin_amdgcn_sched_barrier(0);

        // O += P V
        bf16x8 pf0 = *(const bf16x8*)&Ps[w][c15][hi * 8];
        bf16x8 pf1 = *(const bf16x8*)&Ps[w][c15][32 + hi * 8];
#pragma unroll
        for (int g = 0; g < 4; ++g) {
            bf16x8 vf0 = *(const bf16x8*)&Vt[g * 16 + c15][hi * 8];
            bf16x8 vf1 = *(const bf16x8*)&Vt[g * 16 + c15][32 + hi * 8];
            O[g] = mfma_bf16(pf0, vf0, O[g]);
            O[g] = mfma_bf16(pf1, vf1, O[g]);
        }
    }

    // finish partial row sums (reduce over the 16 lanes sharing a row group)
#pragma unroll
    for (int rg = 0; rg < 4; ++rg) {
        float s = ls[rg];
        s += __shfl_xor(s, 1);
        s += __shfl_xor(s, 2);
        s += __shfl_xor(s, 4);
        s += __shfl_xor(s, 8);
        if (c15 == 0)
            atomicAdd(&lacc[h * NE + q0 + w * 16 + hi * 4 + rg], s);
    }

#pragma unroll
    for (int g = 0; g < 4; ++g)
#pragma unroll
        for (int rg = 0; rg < 4; ++rg) {
            int row = q0 + w * 16 + hi * 4 + rg;
            int col = h * 64 + g * 16 + c15;
            atomicAdd(&Oacc[(long)row * 256 + col], O[g][rg]);
        }
}

// ctx = bf16(Oacc / lacc)  — one float4 per thread, 2048 blocks x 256
__global__ __launch_bounds__(256)
void attn_norm_kernel(const float* __restrict__ Oacc, const float* __restrict__ lacc,
                      bf16_t* __restrict__ ctx) {
    int i = blockIdx.x * 256 + threadIdx.x;   // 0 .. 524287 (float4 slots)
    int row = i >> 6;
    int h = (i & 63) >> 4;
    float rl = 1.0f / lacc[h * NE + row];
    float4 o = ((const float4*)Oacc)[i];
    bf16x4 c;
    c[0] = (bf16_t)(o.x * rl); c[1] = (bf16_t)(o.y * rl);
    c[2] = (bf16_t)(o.z * rl); c[3] = (bf16_t)(o.w * rl);
    ((bf16x4*)ctx)[i] = c;
}

// ---------------------------------------------------------------------------
// LayerNorm over rows of 256: out = LN(x + y) * g + b; optional bf16 copy
// ---------------------------------------------------------------------------
__global__ __launch_bounds__(256)
void ln_kernel(const float* __restrict__ x, const float* __restrict__ y,
               const float* __restrict__ g, const float* __restrict__ b,
               float* __restrict__ outf, bf16_t* __restrict__ outb) {
    int row = blockIdx.x * 4 + (threadIdx.x >> 6);
    int l = threadIdx.x & 63;
    float4 v = ((const float4*)&x[(long)row * 256])[l];
    float4 uu = ((const float4*)&y[(long)row * 256])[l];
    float a0 = v.x + uu.x, a1 = v.y + uu.y, a2 = v.z + uu.z, a3 = v.w + uu.w;

    float s = a0 + a1 + a2 + a3;
#pragma unroll
    for (int off = 1; off < 64; off <<= 1) s += __shfl_xor(s, off);
    float mu = s * (1.0f / 256.0f);

    float d0 = a0 - mu, d1 = a1 - mu, d2 = a2 - mu, d3 = a3 - mu;
    float q = d0 * d0 + d1 * d1 + d2 * d2 + d3 * d3;
#pragma unroll
    for (int off = 1; off < 64; off <<= 1) q += __shfl_xor(q, off);
    float rs = rsqrtf(q * (1.0f / 256.0f) + 1e-5f);

    float4 gg = ((const float4*)g)[l];
    float4 bb = ((const float4*)b)[l];
    float o0 = d0 * rs * gg.x + bb.x;
    float o1 = d1 * rs * gg.y + bb.y;
    float o2 = d2 * rs * gg.z + bb.z;
    float o3 = d3 * rs * gg.w + bb.w;
    float4 ov; ov.x = o0; ov.y = o1; ov.z = o2; ov.w = o3;
    ((float4*)&outf[(long)row * 256])[l] = ov;
    if (outb) {
        bf16x4 ob;
        ob[0] = (bf16_t)o0; ob[1] = (bf16_t)o1; ob[2] = (bf16_t)o2; ob[3] = (bf16_t)o3;
        ((bf16x4*)&outb[(long)row * 256])[l] = ob;
    }
}

// ---------------------------------------------------------------------------
// scatter-add e rows into per-node accumulators (+counts)
// ---------------------------------------------------------------------------
__global__ __launch_bounds__(256)
void scatter_kernel(const float* __restrict__ e, const int* __restrict__ ei,
                    float* __restrict__ acc, float* __restrict__ cnt) {
    int edge = blockIdx.x;
    int dst = ei[NE + edge];
    int t = threadIdx.x;
    atomicAdd(&acc[(long)dst * 256 + t], e[(long)edge * 256 + t]);
    if (t == 0) atomicAdd(&cnt[dst], 1.0f);
}

// updates = acc / max(cnt,1) -> bf16
__global__ __launch_bounds__(256)
void upd_kernel(const float* __restrict__ acc, const float* __restrict__ cnt,
                bf16_t* __restrict__ ub) {
    int i = blockIdx.x * 256 + threadIdx.x;
    int row = i >> 8;
    ub[i] = (bf16_t)(acc[i] / fmaxf(cnt[row], 1.0f));
}

// ---------------------------------------------------------------------------
extern "C" void kernel_launch(void* const* d_in, const int* in_sizes, int n_in,
                              void* d_out, int out_size, void* d_ws, size_t ws_size,
                              hipStream_t stream) {
    const float* node_features = (const float*)d_in[0];
    const float* edge_features = (const float*)d_in[1];
    const float* in_proj_w  = (const float*)d_in[2];
    const float* in_proj_b  = (const float*)d_in[3];
    const float* out_proj_w = (const float*)d_in[4];
    const float* out_proj_b = (const float*)d_in[5];
    const float* mlp_w1 = (const float*)d_in[6];
    const float* mlp_b1 = (const float*)d_in[7];
    const float* mlp_w2 = (const float*)d_in[8];
    const float* mlp_b2 = (const float*)d_in[9];
    const float* nu_w   = (const float*)d_in[10];
    const float* nu_b   = (const float*)d_in[11];
    const float* ln1_g  = (const float*)d_in[12];
    const float* ln1_b  = (const float*)d_in[13];
    const float* ln2_g  = (const float*)d_in[14];
    const float* ln2_b  = (const float*)d_in[15];
    const int*   edge_index = (const int*)d_in[16];

    char* ws = (char*)d_ws;
    size_t off = 0;
    auto alloc = [&](size_t bytes) {
        char* p = ws + off;
        off = (off + bytes + 255) & ~(size_t)255;
        return p;
    };
    bf16_t* ebf   = (bf16_t*)alloc(NE * HH * 2);
    bf16_t* bwq   = (bf16_t*)alloc(768 * 256 * 2);
    bf16_t* bwo   = (bf16_t*)alloc(256 * 256 * 2);
    bf16_t* bw1   = (bf16_t*)alloc(256 * 256 * 2);
    bf16_t* bw2   = (bf16_t*)alloc(256 * 256 * 2);
    bf16_t* bwn   = (bf16_t*)alloc(256 * 256 * 2);
    bf16_t* qkv   = (bf16_t*)alloc((size_t)NE * 768 * 2);
    bf16_t* ctx   = (bf16_t*)alloc((size_t)NE * HH * 2);
    float*  Oacc  = (float*)alloc((size_t)(NE * HH + NSPLIT * NE) * 4); // O + l
    float*  lacc  = Oacc + (size_t)NE * HH;
    float*  attended = (float*)alloc((size_t)NE * HH * 4);
    float*  e1f   = (float*)alloc((size_t)NE * HH * 4);
    bf16_t* e1b   = (bf16_t*)alloc((size_t)NE * HH * 2);
    bf16_t* hbuf  = (bf16_t*)alloc((size_t)NE * HH * 2);
    float*  mlpout = (float*)alloc((size_t)NE * HH * 4);
    float*  acc   = (float*)alloc((size_t)(NN * HH + NN) * 4);
    float*  cnt   = acc + (size_t)NN * HH;
    bf16_t* updb  = (bf16_t*)alloc((size_t)NN * HH * 2);

    float* nout = (float*)d_out;
    float* eout = (float*)d_out + (size_t)NN * HH;

    convert_kernel<<<2048, 256, 0, stream>>>(edge_features, in_proj_w, out_proj_w,
                                             mlp_w1, mlp_w2, nu_w,
                                             ebf, bwq, bwo, bw1, bw2, bwn);

    // qkv = ebf @ in_proj_w^T + b  -> bf16 [NE,768]
    gemm_kernel<0, 1><<<dim3(NE / 64, 768 / 64), 256, 0, stream>>>(
        ebf, bwq, in_proj_b, qkv, nullptr, NE, 768, 256);

    // zero attention accumulators (harness poisons ws; must re-zero every call)
    hipMemsetAsync(Oacc, 0, (size_t)(NE * HH + NSPLIT * NE) * 4, stream);

    attn_kernel<<<dim3(256, NSPLIT), 512, 0, stream>>>(qkv, Oacc, lacc);
    attn_norm_kernel<<<2048, 256, 0, stream>>>(Oacc, lacc, ctx);

    // attended = ctx @ out_proj_w^T + b -> fp32
    gemm_kernel<0, 0><<<dim3(NE / 64, 256 / 64), 256, 0, stream>>>(
        ctx, bwo, out_proj_b, attended, nullptr, NE, 256, 256);

    // e1 = LN(edge_features + attended)
    ln_kernel<<<NE / 4, 256, 0, stream>>>(edge_features, attended, ln1_g, ln1_b,
                                          e1f, e1b);

    // h = relu(e1 @ w1^T + b1) -> bf16
    gemm_kernel<1, 1><<<dim3(NE / 64, 256 / 64), 256, 0, stream>>>(
        e1b, bw1, mlp_b1, hbuf, nullptr, NE, 256, 256);

    // mlpout = h @ w2^T + b2 -> fp32
    gemm_kernel<0, 0><<<dim3(NE / 64, 256 / 64), 256, 0, stream>>>(
        hbuf, bw2, mlp_b2, mlpout, nullptr, NE, 256, 256);

    // e = LN(e1 + mlpout) -> d_out (second output)
    ln_kernel<<<NE / 4, 256, 0, stream>>>(e1f, mlpout, ln2_g, ln2_b,
                                          eout, (bf16_t*)nullptr);

    // scatter mean
    hipMemsetAsync(acc, 0, (size_t)(NN * HH + NN) * 4, stream);
    scatter_kernel<<<NE, 256, 0, stream>>>(eout, edge_index, acc, cnt);
    upd_kernel<<<NN * HH / 256, 256, 0, stream>>>(acc, cnt, updb);

    // n = node_features + relu(updates @ nu_w^T + nu_b) -> d_out (first output)
    gemm_kernel<0, 2><<<dim3(NN / 64, 256 / 64), 256, 0, stream>>>(
        updb, bwn, nu_b, nout, node_features, NN, 256, 256);
}

// Round 3
// 147.642 us; speedup vs baseline: 1.7984x; 1.4255x over previous
//
#include <hip/hip_runtime.h>

typedef __bf16 bf16_t;
typedef __bf16 bf16x8 __attribute__((ext_vector_type(8)));
typedef __bf16 bf16x4 __attribute__((ext_vector_type(4)));
typedef unsigned short u16x8 __attribute__((ext_vector_type(8)));
typedef unsigned int u32x4 __attribute__((ext_vector_type(4)));
typedef float f32x4 __attribute__((ext_vector_type(4)));
typedef float f32x16 __attribute__((ext_vector_type(16)));
typedef int i32x2 __attribute__((ext_vector_type(2)));

#define NE 8192
#define NN 2048
#define HH 256
#define NSPLIT 4
// 0.125 * log2(e): folded into Q so P = exp2(S)
#define QSCALE 0.18033688011112042f

#if __has_builtin(__builtin_amdgcn_exp2f)
#define EXP2(x) __builtin_amdgcn_exp2f(x)
#else
#define EXP2(x) exp2f(x)
#endif

__device__ inline f32x4 mfma16(bf16x8 a, bf16x8 b, f32x4 c) {
    return __builtin_amdgcn_mfma_f32_16x16x32_bf16(a, b, c, 0, 0, 0);
}
__device__ inline f32x16 mfma32(bf16x8 a, bf16x8 b, f32x16 c) {
    return __builtin_amdgcn_mfma_f32_32x32x16_bf16(a, b, c, 0, 0, 0);
}
__device__ inline unsigned cvtpk(float lo, float hi) {
    unsigned r;
    asm("v_cvt_pk_bf16_f32 %0, %1, %2" : "=v"(r) : "v"(lo), "v"(hi));
    return r;
}

// ---------------------------------------------------------------------------
// convert fp32 -> bf16 for edge_features + 5 weight matrices
// ---------------------------------------------------------------------------
__device__ inline bf16x4 cvt4(float4 v) {
    bf16x4 o;
    o[0] = (bf16_t)v.x; o[1] = (bf16_t)v.y; o[2] = (bf16_t)v.z; o[3] = (bf16_t)v.w;
    return o;
}

__global__ __launch_bounds__(256)
void convert_kernel(const float* __restrict__ ef, const float* __restrict__ wq,
                    const float* __restrict__ wo, const float* __restrict__ w1,
                    const float* __restrict__ w2, const float* __restrict__ wn,
                    bf16_t* __restrict__ ebf, bf16_t* __restrict__ bwq,
                    bf16_t* __restrict__ bwo, bf16_t* __restrict__ bw1,
                    bf16_t* __restrict__ bw2, bf16_t* __restrict__ bwn) {
    int i = blockIdx.x * 256 + threadIdx.x;   // 0 .. 524287
    ((bf16x4*)ebf)[i] = cvt4(((const float4*)ef)[i]);
    if (i < 49152) ((bf16x4*)bwq)[i] = cvt4(((const float4*)wq)[i]);
    if (i < 16384) {
        ((bf16x4*)bwo)[i] = cvt4(((const float4*)wo)[i]);
        ((bf16x4*)bw1)[i] = cvt4(((const float4*)w1)[i]);
        ((bf16x4*)bw2)[i] = cvt4(((const float4*)w2)[i]);
        ((bf16x4*)bwn)[i] = cvt4(((const float4*)wn)[i]);
    }
}

// ---------------------------------------------------------------------------
// Generic bf16 GEMM: C = act(A * B^T + bias)  [A: MxK, B: NxK row-major]
// 64x64 tile, BK=64, 256 threads (4 waves, each a 32x32 quadrant)
// QSC: scale cols<256 by QSCALE (folds attention 1/sqrt(d)*log2e into Q)
// ---------------------------------------------------------------------------
template<int ACT, int OUTKIND, int QSC = 0>
__global__ __launch_bounds__(256)
void gemm_kernel(const bf16_t* __restrict__ A, const bf16_t* __restrict__ B,
                 const float* __restrict__ bias, void* __restrict__ out,
                 const float* __restrict__ resid, int M, int N, int K) {
    __shared__ bf16_t As[64][72];
    __shared__ bf16_t Bs[64][72];
    int tid = threadIdx.x;
    int w = tid >> 6, l = tid & 63, hi = l >> 4, c15 = l & 15;
    int wr = w >> 1, wc = w & 1;
    int brow = blockIdx.x * 64, bcol = blockIdx.y * 64;
    int r = tid >> 2, s = tid & 3;

    f32x4 acc[2][2] = {};

    for (int k0 = 0; k0 < K; k0 += 64) {
        __syncthreads();
        bf16x8 a0 = *(const bf16x8*)&A[(long)(brow + r) * K + k0 + s * 16];
        bf16x8 a1 = *(const bf16x8*)&A[(long)(brow + r) * K + k0 + s * 16 + 8];
        bf16x8 b0 = *(const bf16x8*)&B[(long)(bcol + r) * K + k0 + s * 16];
        bf16x8 b1 = *(const bf16x8*)&B[(long)(bcol + r) * K + k0 + s * 16 + 8];
        *(bf16x8*)&As[r][s * 16]     = a0;
        *(bf16x8*)&As[r][s * 16 + 8] = a1;
        *(bf16x8*)&Bs[r][s * 16]     = b0;
        *(bf16x8*)&Bs[r][s * 16 + 8] = b1;
        __syncthreads();
#pragma unroll
        for (int c = 0; c < 2; ++c) {
            bf16x8 af0 = *(const bf16x8*)&As[wr * 32 + c15][c * 32 + hi * 8];
            bf16x8 af1 = *(const bf16x8*)&As[wr * 32 + 16 + c15][c * 32 + hi * 8];
            bf16x8 bf0 = *(const bf16x8*)&Bs[wc * 32 + c15][c * 32 + hi * 8];
            bf16x8 bf1 = *(const bf16x8*)&Bs[wc * 32 + 16 + c15][c * 32 + hi * 8];
            acc[0][0] = mfma16(af0, bf0, acc[0][0]);
            acc[0][1] = mfma16(af0, bf1, acc[0][1]);
            acc[1][0] = mfma16(af1, bf0, acc[1][0]);
            acc[1][1] = mfma16(af1, bf1, acc[1][1]);
        }
    }

    float sc = (QSC && bcol < 256) ? QSCALE : 1.0f;
#pragma unroll
    for (int i = 0; i < 2; ++i)
#pragma unroll
        for (int j = 0; j < 2; ++j)
#pragma unroll
            for (int rg = 0; rg < 4; ++rg) {
                int row = brow + wr * 32 + i * 16 + hi * 4 + rg;
                int col = bcol + wc * 32 + j * 16 + c15;
                float v = (acc[i][j][rg] + bias[col]) * sc;
                if (ACT) v = fmaxf(v, 0.0f);
                if (OUTKIND == 0) {
                    ((float*)out)[(long)row * N + col] = v;
                } else if (OUTKIND == 1) {
                    ((bf16_t*)out)[(long)row * N + col] = (bf16_t)v;
                } else {
                    ((float*)out)[(long)row * N + col] =
                        resid[(long)row * N + col] + fmaxf(v, 0.0f);
                }
            }
}

// ---------------------------------------------------------------------------
// Flash attention, 32x32x16 MFMA, swapped QK^T (S^T = K Q^T) so softmax is
// lane-local and P goes to the PV B-operand via cvt_pk + permlane32_swap —
// no P LDS round-trip. Q pre-scaled by 0.125*log2e so P = exp2(S).
// Block: 256 thr = 4 waves, each wave 64 q-rows -> q-block 256.
// grid = dim3(128, NSPLIT): x -> (h = &3, qb = >>2), y -> kv split.
// No-max softmax (scores small): partials summed across splits in merge.
// ---------------------------------------------------------------------------
__global__ __launch_bounds__(256, 2)
void attn_kernel(const bf16_t* __restrict__ qkv, float* __restrict__ Opart,
                 float* __restrict__ lpart) {
    __shared__ char smem[36864];
    bf16_t (*Ks)[64][72] = (bf16_t (*)[64][72])smem;             // [buf][kv][d]
    bf16_t (*Vt)[64][72] = (bf16_t (*)[64][72])(smem + 18432);   // [buf][d][kv]

    int h = blockIdx.x & 3, qb = blockIdx.x >> 2, sp = blockIdx.y;
    int q0 = qb * 256;
    int tid = threadIdx.x;
    int wv = tid >> 6, l = tid & 63, l31 = l & 31, h8 = l >> 5;

    // Q fragments (B-operand): lane holds Q[q0+wv*64+qt*32+l31][dc*16+h8*8+j]
    bf16x8 qf[2][4];
#pragma unroll
    for (int qt = 0; qt < 2; ++qt)
#pragma unroll
        for (int dc = 0; dc < 4; ++dc)
            qf[qt][dc] = *(const bf16x8*)&qkv[
                (size_t)(q0 + wv * 64 + qt * 32 + l31) * 768 + h * 64 + dc * 16 + h8 * 8];

    f32x16 o[2][2];   // [dt][qt] : O^T[d = dt*32+rowmap][q = qt*32+l31]
#pragma unroll
    for (int a = 0; a < 2; ++a)
#pragma unroll
        for (int b = 0; b < 2; ++b)
#pragma unroll
            for (int r = 0; r < 16; ++r) o[a][b][r] = 0.f;
    float ls[2] = {0.f, 0.f};

    int kr = tid >> 2, ksc = tid & 3;   // K staging: row kr, 16-elem chunk ksc
    int vp = tid & 31, vc = tid >> 5;   // V staging: kv pair 2vp, d-chunk vc(8)
    int kv0 = sp * (NE / NSPLIT);
    const int NT = (NE / NSPLIT) / 64;

    bf16x8 kst0, kst1, vst0, vst1;
    {   // global load tile 0
        const bf16_t* ksrc = &qkv[(size_t)(kv0 + kr) * 768 + 256 + h * 64 + ksc * 16];
        kst0 = *(const bf16x8*)ksrc; kst1 = *(const bf16x8*)(ksrc + 8);
        const bf16_t* vsrc = &qkv[(size_t)(kv0 + 2 * vp) * 768 + 512 + h * 64 + vc * 8];
        vst0 = *(const bf16x8*)vsrc; vst1 = *(const bf16x8*)(vsrc + 768);
    }
    {   // stage into buf 0
        *(bf16x8*)&Ks[0][kr][ksc * 16]     = kst0;
        *(bf16x8*)&Ks[0][kr][ksc * 16 + 8] = kst1;
        u16x8 ua = __builtin_bit_cast(u16x8, vst0), ub = __builtin_bit_cast(u16x8, vst1);
#pragma unroll
        for (int j = 0; j < 8; ++j) {
            unsigned wd = (unsigned)ua[j] | ((unsigned)ub[j] << 16);
            *(unsigned*)&Vt[0][vc * 8 + j][2 * vp] = wd;
        }
    }

    for (int t = 0; t < NT; ++t) {
        int cur = t & 1;
        __syncthreads();   // staged buf visible; nothing else in flight
        if (t + 1 < NT) {  // issue next tile's global loads (latency hidden by compute)
            int kt = kv0 + (t + 1) * 64;
            const bf16_t* ksrc = &qkv[(size_t)(kt + kr) * 768 + 256 + h * 64 + ksc * 16];
            kst0 = *(const bf16x8*)ksrc; kst1 = *(const bf16x8*)(ksrc + 8);
            const bf16_t* vsrc = &qkv[(size_t)(kt + 2 * vp) * 768 + 512 + h * 64 + vc * 8];
            vst0 = *(const bf16x8*)vsrc; vst1 = *(const bf16x8*)(vsrc + 768);
        }

#pragma unroll
        for (int kvt = 0; kvt < 2; ++kvt) {
            // K fragments (A-operand): rows kv = kvt*32+l31, k = d
            bf16x8 kf[4];
#pragma unroll
            for (int dc = 0; dc < 4; ++dc)
                kf[dc] = *(const bf16x8*)&Ks[cur][kvt * 32 + l31][dc * 16 + h8 * 8];
            // S^T = K Q^T
            f32x16 s[2];
#pragma unroll
            for (int qt = 0; qt < 2; ++qt) {
#pragma unroll
                for (int r = 0; r < 16; ++r) s[qt][r] = 0.f;
#pragma unroll
                for (int dc = 0; dc < 4; ++dc)
                    s[qt] = mfma32(kf[dc], qf[qt][dc], s[qt]);
            }
            // P = exp2(S), row sums, pack P into PV B-fragments in-register
            bf16x8 bfr[2][2];
#pragma unroll
            for (int qt = 0; qt < 2; ++qt) {
                float p[16];
#pragma unroll
                for (int r = 0; r < 16; ++r) { p[r] = EXP2(s[qt][r]); ls[qt] += p[r]; }
#pragma unroll
                for (int half = 0; half < 2; ++half) {
                    i32x2 r0 = __builtin_amdgcn_permlane32_swap(
                        (int)cvtpk(p[8 * half + 0], p[8 * half + 1]),
                        (int)cvtpk(p[8 * half + 4], p[8 * half + 5]), false, false);
                    i32x2 r1 = __builtin_amdgcn_permlane32_swap(
                        (int)cvtpk(p[8 * half + 2], p[8 * half + 3]),
                        (int)cvtpk(p[8 * half + 6], p[8 * half + 7]), false, false);
                    u32x4 wds;
                    wds[0] = (unsigned)r0[0]; wds[1] = (unsigned)r1[0];
                    wds[2] = (unsigned)r0[1]; wds[3] = (unsigned)r1[1];
                    bfr[qt][half] = __builtin_bit_cast(bf16x8, wds);
                }
            }
            // O^T += V^T P^T
#pragma unroll
            for (int dt = 0; dt < 2; ++dt) {
                bf16x8 vf[2];
#pragma unroll
                for (int half = 0; half < 2; ++half)
                    vf[half] = *(const bf16x8*)&Vt[cur][dt * 32 + l31][(kvt * 2 + half) * 16 + h8 * 8];
#pragma unroll
                for (int qt = 0; qt < 2; ++qt)
#pragma unroll
                    for (int half = 0; half < 2; ++half)
                        o[dt][qt] = mfma32(vf[half], bfr[qt][half], o[dt][qt]);
            }
        }

        if (t + 1 < NT) {  // stage next tile into the other buffer
            int nb = (t + 1) & 1;
            *(bf16x8*)&Ks[nb][kr][ksc * 16]     = kst0;
            *(bf16x8*)&Ks[nb][kr][ksc * 16 + 8] = kst1;
            u16x8 ua = __builtin_bit_cast(u16x8, vst0), ub = __builtin_bit_cast(u16x8, vst1);
#pragma unroll
            for (int j = 0; j < 8; ++j) {
                unsigned wd = (unsigned)ua[j] | ((unsigned)ub[j] << 16);
                *(unsigned*)&Vt[nb][vc * 8 + j][2 * vp] = wd;
            }
        }
    }

    // row-sum partials: lane l and l+32 hold complementary kv subsets
#pragma unroll
    for (int qt = 0; qt < 2; ++qt) {
        float lt = ls[qt] + __shfl_xor(ls[qt], 32);
        if (l < 32)
            lpart[((size_t)sp * 4 + h) * NE + q0 + wv * 64 + qt * 32 + l31] = lt;
    }

    // O^T -> LDS (stride 68 f32) -> coalesced float4 partial stores
    float* Of = (float*)smem;
#pragma unroll
    for (int pass = 0; pass < 2; ++pass) {
        __syncthreads();
        if ((wv >> 1) == pass) {
#pragma unroll
            for (int dt = 0; dt < 2; ++dt)
#pragma unroll
                for (int qt = 0; qt < 2; ++qt)
#pragma unroll
                    for (int r = 0; r < 16; ++r) {
                        int qrel = (wv & 1) * 64 + qt * 32 + l31;
                        int d = dt * 32 + (r & 3) + 8 * (r >> 2) + 4 * h8;
                        Of[qrel * 68 + d] = o[dt][qt][r];
                    }
        }
        __syncthreads();
        {
            int rr = tid >> 1, hf = tid & 1;
            float* dst = &Opart[(size_t)sp * NE * 256 +
                                (size_t)(q0 + pass * 128 + rr) * 256 + h * 64 + hf * 32];
#pragma unroll
            for (int i = 0; i < 8; ++i) {
                float4 v = *(float4*)&Of[rr * 68 + hf * 32 + i * 4];
                *(float4*)&dst[i * 4] = v;
            }
        }
    }
}

// ctx = bf16( sum_sp Opart / sum_sp lpart )
__global__ __launch_bounds__(256)
void attn_merge_kernel(const float* __restrict__ Opart, const float* __restrict__ lpart,
                       bf16_t* __restrict__ ctx) {
    int i = blockIdx.x * 256 + threadIdx.x;   // float4 id, 0..524287
    int q = i >> 6, c4 = i & 63, h = c4 >> 4;
    float4 sum = {0.f, 0.f, 0.f, 0.f};
    float lsum = 0.f;
#pragma unroll
    for (int sp = 0; sp < NSPLIT; ++sp) {
        float4 v = ((const float4*)Opart)[(size_t)sp * (NE * 64) + i];
        sum.x += v.x; sum.y += v.y; sum.z += v.z; sum.w += v.w;
        lsum += lpart[((size_t)sp * 4 + h) * NE + q];
    }
    float rl = 1.0f / lsum;
    bf16x4 c;
    c[0] = (bf16_t)(sum.x * rl); c[1] = (bf16_t)(sum.y * rl);
    c[2] = (bf16_t)(sum.z * rl); c[3] = (bf16_t)(sum.w * rl);
    ((bf16x4*)ctx)[i] = c;
}

// ---------------------------------------------------------------------------
// LayerNorm over rows of 256: out = LN(x + y) * g + b; optional bf16 copy
// ---------------------------------------------------------------------------
__global__ __launch_bounds__(256)
void ln_kernel(const float* __restrict__ x, const float* __restrict__ y,
               const float* __restrict__ g, const float* __restrict__ b,
               float* __restrict__ outf, bf16_t* __restrict__ outb) {
    int row = blockIdx.x * 4 + (threadIdx.x >> 6);
    int l = threadIdx.x & 63;
    float4 v = ((const float4*)&x[(long)row * 256])[l];
    float4 uu = ((const float4*)&y[(long)row * 256])[l];
    float a0 = v.x + uu.x, a1 = v.y + uu.y, a2 = v.z + uu.z, a3 = v.w + uu.w;

    float s = a0 + a1 + a2 + a3;
#pragma unroll
    for (int off = 1; off < 64; off <<= 1) s += __shfl_xor(s, off);
    float mu = s * (1.0f / 256.0f);

    float d0 = a0 - mu, d1 = a1 - mu, d2 = a2 - mu, d3 = a3 - mu;
    float q = d0 * d0 + d1 * d1 + d2 * d2 + d3 * d3;
#pragma unroll
    for (int off = 1; off < 64; off <<= 1) q += __shfl_xor(q, off);
    float rs = rsqrtf(q * (1.0f / 256.0f) + 1e-5f);

    float4 gg = ((const float4*)g)[l];
    float4 bb = ((const float4*)b)[l];
    float o0 = d0 * rs * gg.x + bb.x;
    float o1 = d1 * rs * gg.y + bb.y;
    float o2 = d2 * rs * gg.z + bb.z;
    float o3 = d3 * rs * gg.w + bb.w;
    float4 ov; ov.x = o0; ov.y = o1; ov.z = o2; ov.w = o3;
    ((float4*)&outf[(long)row * 256])[l] = ov;
    if (outb) {
        bf16x4 ob;
        ob[0] = (bf16_t)o0; ob[1] = (bf16_t)o1; ob[2] = (bf16_t)o2; ob[3] = (bf16_t)o3;
        ((bf16x4*)&outb[(long)row * 256])[l] = ob;
    }
}

// ---------------------------------------------------------------------------
// scatter-add e rows into per-node accumulators (+counts)
// ---------------------------------------------------------------------------
__global__ __launch_bounds__(256)
void scatter_kernel(const float* __restrict__ e, const int* __restrict__ ei,
                    float* __restrict__ acc, float* __restrict__ cnt) {
    int edge = blockIdx.x;
    int dst = ei[NE + edge];
    int t = threadIdx.x;
    atomicAdd(&acc[(long)dst * 256 + t], e[(long)edge * 256 + t]);
    if (t == 0) atomicAdd(&cnt[dst], 1.0f);
}

// updates = acc / max(cnt,1) -> bf16
__global__ __launch_bounds__(256)
void upd_kernel(const float* __restrict__ acc, const float* __restrict__ cnt,
                bf16_t* __restrict__ ub) {
    int i = blockIdx.x * 256 + threadIdx.x;
    int row = i >> 8;
    ub[i] = (bf16_t)(acc[i] / fmaxf(cnt[row], 1.0f));
}

// ---------------------------------------------------------------------------
extern "C" void kernel_launch(void* const* d_in, const int* in_sizes, int n_in,
                              void* d_out, int out_size, void* d_ws, size_t ws_size,
                              hipStream_t stream) {
    const float* node_features = (const float*)d_in[0];
    const float* edge_features = (const float*)d_in[1];
    const float* in_proj_w  = (const float*)d_in[2];
    const float* in_proj_b  = (const float*)d_in[3];
    const float* out_proj_w = (const float*)d_in[4];
    const float* out_proj_b = (const float*)d_in[5];
    const float* mlp_w1 = (const float*)d_in[6];
    const float* mlp_b1 = (const float*)d_in[7];
    const float* mlp_w2 = (const float*)d_in[8];
    const float* mlp_b2 = (const float*)d_in[9];
    const float* nu_w   = (const float*)d_in[10];
    const float* nu_b   = (const float*)d_in[11];
    const float* ln1_g  = (const float*)d_in[12];
    const float* ln1_b  = (const float*)d_in[13];
    const float* ln2_g  = (const float*)d_in[14];
    const float* ln2_b  = (const float*)d_in[15];
    const int*   edge_index = (const int*)d_in[16];

    char* ws = (char*)d_ws;
    size_t off = 0;
    auto alloc = [&](size_t bytes) {
        char* p = ws + off;
        off = (off + bytes + 255) & ~(size_t)255;
        return p;
    };
    // region A: persistent across the whole launch
    bf16_t* ebf   = (bf16_t*)alloc(NE * HH * 2);
    bf16_t* bwq   = (bf16_t*)alloc(768 * 256 * 2);
    bf16_t* bwo   = (bf16_t*)alloc(256 * 256 * 2);
    bf16_t* bw1   = (bf16_t*)alloc(256 * 256 * 2);
    bf16_t* bw2   = (bf16_t*)alloc(256 * 256 * 2);
    bf16_t* bwn   = (bf16_t*)alloc(256 * 256 * 2);
    bf16_t* qkv   = (bf16_t*)alloc((size_t)NE * 768 * 2);
    bf16_t* ctx   = (bf16_t*)alloc((size_t)NE * HH * 2);
    float*  lpart = (float*)alloc((size_t)NSPLIT * 4 * NE * 4);
    float*  acc   = (float*)alloc((size_t)(NN * HH + NN) * 4);
    float*  cnt   = acc + (size_t)NN * HH;
    bf16_t* updb  = (bf16_t*)alloc((size_t)NN * HH * 2);
    // region B: Opart's lifetime (attn -> merge) ends before attended/e1f/... begin
    size_t offB = off;
    float*  Opart = (float*)alloc((size_t)NSPLIT * NE * HH * 4);   // 33.5 MB
    off = offB;  // union: reuse for the post-attention activations
    float*  attended = (float*)alloc((size_t)NE * HH * 4);
    float*  e1f   = (float*)alloc((size_t)NE * HH * 4);
    bf16_t* e1b   = (bf16_t*)alloc((size_t)NE * HH * 2);
    bf16_t* hbuf  = (bf16_t*)alloc((size_t)NE * HH * 2);
    float*  mlpout = (float*)alloc((size_t)NE * HH * 4);

    float* nout = (float*)d_out;
    float* eout = (float*)d_out + (size_t)NN * HH;

    convert_kernel<<<2048, 256, 0, stream>>>(edge_features, in_proj_w, out_proj_w,
                                             mlp_w1, mlp_w2, nu_w,
                                             ebf, bwq, bwo, bw1, bw2, bwn);

    // qkv = ebf @ in_proj_w^T + b  -> bf16 [NE,768]; Q cols pre-scaled
    gemm_kernel<0, 1, 1><<<dim3(NE / 64, 768 / 64), 256, 0, stream>>>(
        ebf, bwq, in_proj_b, qkv, nullptr, NE, 768, 256);

    attn_kernel<<<dim3(128, NSPLIT), 256, 0, stream>>>(qkv, Opart, lpart);
    attn_merge_kernel<<<2048, 256, 0, stream>>>(Opart, lpart, ctx);

    // attended = ctx @ out_proj_w^T + b -> fp32
    gemm_kernel<0, 0><<<dim3(NE / 64, 256 / 64), 256, 0, stream>>>(
        ctx, bwo, out_proj_b, attended, nullptr, NE, 256, 256);

    // e1 = LN(edge_features + attended)
    ln_kernel<<<NE / 4, 256, 0, stream>>>(edge_features, attended, ln1_g, ln1_b,
                                          e1f, e1b);

    // h = relu(e1 @ w1^T + b1) -> bf16
    gemm_kernel<1, 1><<<dim3(NE / 64, 256 / 64), 256, 0, stream>>>(
        e1b, bw1, mlp_b1, hbuf, nullptr, NE, 256, 256);

    // mlpout = h @ w2^T + b2 -> fp32
    gemm_kernel<0, 0><<<dim3(NE / 64, 256 / 64), 256, 0, stream>>>(
        hbuf, bw2, mlp_b2, mlpout, nullptr, NE, 256, 256);

    // e = LN(e1 + mlpout) -> d_out (second output)
    ln_kernel<<<NE / 4, 256, 0, stream>>>(e1f, mlpout, ln2_g, ln2_b,
                                          eout, (bf16_t*)nullptr);

    // scatter mean
    hipMemsetAsync(acc, 0, (size_t)(NN * HH + NN) * 4, stream);
    scatter_kernel<<<NE, 256, 0, stream>>>(eout, edge_index, acc, cnt);
    upd_kernel<<<NN * HH / 256, 256, 0, stream>>>(acc, cnt, updb);

    // n = node_features + relu(updates @ nu_w^T + nu_b) -> d_out (first output)
    gemm_kernel<0, 2><<<dim3(NN / 64, 256 / 64), 256, 0, stream>>>(
        updb, bwn, nu_b, nout, node_features, NN, 256, 256);
}